// Round 8
// baseline (261.953 us; speedup 1.0000x reference)
//
#include <hip/hip_runtime.h>
#include <stdint.h>

typedef int v4i __attribute__((ext_vector_type(4)));

// Problem constants (from reference)
constexpr int G = 7, B = 8, M = 512, N = 512, K = 1024;
constexpr int GBn = G * B;                       // 56
// X_ZP = -66, Y_ZP = 160 (hardcoded in reference)
// With y' = y - 128:  sum (x-X)(y-Y) = dot(x,y') - 32*rowsum_x + 66*colsum_y' - 2162688

// ws layout: yt [b][n][k] int8 (y-128), then csp[16][B*N] per-k-tile colsum partials
constexpr size_t YT_BYTES = (size_t)B * N * K;   // 4,194,304
constexpr size_t CSP_CNT  = (size_t)16 * B * N;  // 65,536 ints
constexpr size_t WS_NEEDED = YT_BYTES + CSP_CNT * 4;

// ---------------------------------------------------------------------------
// K1: transpose + pack y:  y[b][k][n] (int32, 0..255)  ->  yt[b][n][k] (int8, y-128)
// plus per-(k-tile, b, n) partial colsums of y' into csp.
// 64x64 tiles through LDS. Grid: (N/64, K/64, B), block 256.
// ---------------------------------------------------------------------------
__global__ __launch_bounds__(256) void transpose_pack_y(const int* __restrict__ y,
                                                        signed char* __restrict__ yt,
                                                        int* __restrict__ csp) {
    __shared__ unsigned char tile[64][80];       // 80 = 5*16: 16B-aligned rows, odd 16-bank phase
    int n0  = blockIdx.x * 64;
    int k0t = blockIdx.y;
    int k0  = k0t * 64;
    int b   = blockIdx.z;
    int t   = threadIdx.x;

    // phase 1: coalesced read along n, pack low bytes (^0x80 == y-128 as i8), 16B to LDS
    int r  = t >> 2;                              // k-local 0..63
    int c0 = (t & 3) * 16;                        // n-local byte offset
    const int* src = y + ((size_t)b * K + k0 + r) * N + n0 + c0;
    uint32_t p[4];
#pragma unroll
    for (int q = 0; q < 4; ++q) {
        int4 v = ((const int4*)src)[q];
        p[q] =  (uint32_t)((v.x & 255) ^ 128)
             | ((uint32_t)((v.y & 255) ^ 128) << 8)
             | ((uint32_t)((v.z & 255) ^ 128) << 16)
             | ((uint32_t)((v.w & 255) ^ 128) << 24);
    }
    *(uint4*)&tile[r][c0] = make_uint4(p[0], p[1], p[2], p[3]);
    __syncthreads();

    // phase 2: gather a column of 16 k-bytes per thread, write 16B contiguous in k
    int nl = t >> 2;                              // n-local 0..63
    int kc = (t & 3) * 16;                        // k-local byte offset
    uint32_t q[4];
    int s = 0;
#pragma unroll
    for (int w = 0; w < 4; ++w) {
        uint32_t b0 = tile[kc + w * 4 + 0][nl];
        uint32_t b1 = tile[kc + w * 4 + 1][nl];
        uint32_t b2 = tile[kc + w * 4 + 2][nl];
        uint32_t b3 = tile[kc + w * 4 + 3][nl];
        s += (int)(signed char)b0 + (int)(signed char)b1
           + (int)(signed char)b2 + (int)(signed char)b3;
        q[w] = b0 | (b1 << 8) | (b2 << 16) | (b3 << 24);
    }
    *(uint4*)(yt + ((size_t)b * N + n0 + nl) * K + k0 + kc) = make_uint4(q[0], q[1], q[2], q[3]);

    // quad-reduce partial colsum (4 threads cover 64 k for one n)
    s += __shfl_xor(s, 1, 64);
    s += __shfl_xor(s, 2, 64);
    if ((t & 3) == 0) csp[(size_t)k0t * (B * N) + b * N + n0 + nl] = s;
}

// ---------------------------------------------------------------------------
// K2 (fused GEMM), round-8: PHASE-SPLIT, barrier-free K-loop.
//
// Session law (R1/R2/R3/R6/R7): step_time = 0.4us + chip_bytes/3.6TB/s,
// invariant to sync/occupancy/stagger/counted-vmcnt. The per-step mix
// (256B-per-4KB strided x reads + global_load_lds B) serves at ~3.6TB/s;
// m13 suggests the pure READ path is ~3.1-3.5TB/s. So: make each phase its
// best pattern and stop paying the mix.
//
// Block = 64m x 512n (full N) for one (gb, mt); 512 threads, 8 waves (2m x
// 4n), wave 32x128 via 2x8 mfma_i32_16x16x64_i8; 2 waves/SIMD -> 256-reg
// budget (R5 proved 128-reg cap kills pipelining; R1 proved 2-wave works).
//
//   PROLOGUE: stream the block's CONTIGUOUS 256KB x panel (sequential 16B/
//     lane loads), pack int32->int8 into a 64KB XOR-swizzled LDS panel,
//     fold rowsums. ONE __syncthreads (the only barrier).
//   K-LOOP (barrier-free, zero HBM): af via ds_read_b128 from the panel;
//     bf per-lane 16B DIRECT from yt (L2-resident, 3.5MB/XCD; 16-row x 64B
//     segments; t*64 -> immediate offsets), register-double-buffered one
//     step ahead (issue t+1 before consuming t => compiler emits counted
//     vmcnt(8) from the register dependence). No global_load_lds, no Bs.
//   EPILOGUE: zero-point correction + scale, coalesced stores.
//
// Panel swizzle: 16B chunk c of row r stored at c ^ (r&7).
//   ds_write_b128: lanes (r 0..7, a8 0..7) -> slot%8 = a8^(r&7): 8 lanes per
//   16B region, even -> conflict-free. ds_read_b128 af: slot%8 =
//   ((t*4+h)^(fr&7))%8 over (fr 0..15, h 0..3): 8 lanes/region, even -> free
//   (same b128 8-region rule R1 measured at 0 conflicts).
// LDS: 64KB panel + 2KB cs + 256B rs -> 66.3KB.
// Grid: 448 = 56 gb x 8 mt, XCD-bijective swizzle: per XCD 7 gb -> 7 yt
// b-slices = 3.5MB < 4MB L2. Fleet-wide phase desync overlaps HBM-heavy
// prologues with L2/MFMA-heavy loops.
// ---------------------------------------------------------------------------
__global__ __launch_bounds__(512, 2) void gemm_fused(const int* __restrict__ x,
                                                     const signed char* __restrict__ yt,
                                                     const int* __restrict__ csp,
                                                     const float* __restrict__ xsp,
                                                     const float* __restrict__ ysp,
                                                     float* __restrict__ out) {
    __shared__ __align__(16) signed char Ap[64][1024];   // 64 KiB swizzled panel
    __shared__ int cs_lds[512];
    __shared__ int rs_lds[64];

    int id  = blockIdx.x;                         // 0..447
    int swz = (id & 7) * 56 + (id >> 3);          // XCD-contiguous chunks (448%8==0, bijective)
    int gb  = swz >> 3;                           // 0..55
    int mt  = swz & 7;                            // 0..7
    int b   = gb & 7;

    int tid = threadIdx.x, wave = tid >> 6, lane = tid & 63;

    // block colsums: each thread sums 16 per-k-tile partials for one n
    {
        int s = 0;
        const int* p = csp + b * N + tid;
#pragma unroll
        for (int kt = 0; kt < 16; ++kt) s += p[(size_t)kt * (B * N)];
        cs_lds[tid] = s;
    }
    float sc = xsp[0] * ysp[0];

    // ---- prologue: stream 256KB contiguous panel, pack -> LDS, rowsums ----
    // thread: row r = tid>>3 (0..63), sub-lane a8 = tid&7.
    // int4 index q = a8*4 + v + 32*w (v 0..3, w 0..7): the 4 v's form one
    // full 16B packed chunk c = a8 + 8w, written with one ds_write_b128.
    int r  = tid >> 3;
    int a8 = tid & 7;
    int rswz = r & 7;
    const int4* Arow = (const int4*)(x + ((size_t)(gb * M + mt * 64 + r)) * K);
    int rsum = 0;
#pragma unroll
    for (int ww = 0; ww < 2; ++ww) {              // two batches of 16 int4 (64 regs)
        int4 v[16];
#pragma unroll
        for (int w4 = 0; w4 < 4; ++w4)
#pragma unroll
            for (int vv = 0; vv < 4; ++vv)
                v[w4 * 4 + vv] = Arow[a8 * 4 + vv + 32 * (ww * 4 + w4)];
#pragma unroll
        for (int w4 = 0; w4 < 4; ++w4) {
            uint32_t pw[4];
#pragma unroll
            for (int vv = 0; vv < 4; ++vv) {
                int4 t = v[w4 * 4 + vv];
                rsum += t.x + t.y + t.z + t.w;
                pw[vv] =  (uint32_t)(t.x & 255)
                       | ((uint32_t)(t.y & 255) << 8)
                       | ((uint32_t)(t.z & 255) << 16)
                       | ((uint32_t)(t.w & 255) << 24);
            }
            int c = a8 + 8 * (ww * 4 + w4);       // logical 16B chunk 0..63
            *(uint4*)&Ap[r][(c ^ rswz) << 4] = make_uint4(pw[0], pw[1], pw[2], pw[3]);
        }
    }
    rsum += __shfl_xor(rsum, 1, 64);
    rsum += __shfl_xor(rsum, 2, 64);
    rsum += __shfl_xor(rsum, 4, 64);
    if ((tid & 7) == 0) rs_lds[r] = rsum;

    __syncthreads();   // the ONLY barrier: panel + rs + cs ready

    // ---- K-loop: barrier-free, A from LDS panel, B direct from L2 ----
    int fr = lane & 15;                           // col-in-tile
    int h  = lane >> 4;                           // k-quad selector 0..3
    int wm = (wave >> 2) * 32;                    // 0 or 32
    int wn = (wave & 3) * 128;                    // 0,128,256,384
    int fswz = fr & 7;                            // row-swizzle for af (wm,16 are 0 mod 8)

    // B fragment bases: lane reads 16B of row (wn + j*16 + fr) at k = t*64 + h*16
    const signed char* Bb[8];
#pragma unroll
    for (int j = 0; j < 8; ++j)
        Bb[j] = yt + ((size_t)(b * N + wn + j * 16 + fr)) * K + h * 16;

    v4i zero = {0, 0, 0, 0};
    v4i acc[2][8];
#pragma unroll
    for (int i = 0; i < 2; ++i)
#pragma unroll
        for (int j = 0; j < 8; ++j) acc[i][j] = zero;

    v4i bf[2][8];                                 // register double-buffer (static idx under unroll)
#pragma unroll
    for (int j = 0; j < 8; ++j) bf[0][j] = *(const v4i*)(Bb[j]);

#pragma unroll
    for (int t = 0; t < 16; ++t) {
        int cur = t & 1;
        // issue t+1's B loads first: they fly under this step's MFMAs;
        // consuming bf[cur] below forces vmcnt(8) (counted, not drain).
        if (t < 15) {
#pragma unroll
            for (int j = 0; j < 8; ++j)
                bf[cur ^ 1][j] = *(const v4i*)(Bb[j] + (t + 1) * 64);
        }

        v4i af[2];
#pragma unroll
        for (int i = 0; i < 2; ++i)
            af[i] = *(const v4i*)&Ap[wm + i * 16 + fr][((t * 4 + h) ^ fswz) << 4];

#pragma unroll
        for (int i = 0; i < 2; ++i)
#pragma unroll
            for (int j = 0; j < 8; ++j)
                acc[i][j] = __builtin_amdgcn_mfma_i32_16x16x64_i8(af[i], bf[cur][j], acc[i][j], 0, 0, 0);
    }

    // ---- epilogue: C = s * (dot - 32*rowsum_x + 66*colsum_y' - 2162688) ----
    int colL = lane & 15;
    int rowQ = (lane >> 4) * 4;
    float* outg = out + (size_t)gb * (M * N) + (size_t)(mt * 64) * N;
#pragma unroll
    for (int i = 0; i < 2; ++i) {
#pragma unroll
        for (int rr = 0; rr < 4; ++rr) {
            int row_l = wm + i * 16 + rowQ + rr;
            int rsv = rs_lds[row_l];
#pragma unroll
            for (int j = 0; j < 8; ++j) {
                int col = wn + j * 16 + colL;
                int tv = acc[i][j][rr] - 32 * rsv + 66 * cs_lds[col] - 2162688;
                outg[(size_t)row_l * N + col] = sc * (float)tv;
            }
        }
    }
}

// ---------------------------------------------------------------------------
// Fallback (only if ws_size is too small): naive but correct.
// sum (x-X)(y-Y) = dot(x,y) - 160*sum_x + 66*sum_y - 10,813,440
// ---------------------------------------------------------------------------
__global__ __launch_bounds__(256) void naive_kernel(const int* __restrict__ x,
                                                    const int* __restrict__ y,
                                                    const float* __restrict__ xsp,
                                                    const float* __restrict__ ysp,
                                                    float* __restrict__ out) {
    size_t idx = (size_t)blockIdx.x * 256 + threadIdx.x;   // over 14,680,064
    int n  = (int)(idx & 511);
    int m  = (int)((idx >> 9) & 511);
    int gb = (int)(idx >> 18);
    int b  = gb & 7;
    const int* xr = x + ((size_t)gb * M + m) * K;
    const int* yc = y + (size_t)b * K * N + n;
    int dot = 0, sx = 0, sy = 0;
    for (int k = 0; k < K; ++k) {
        int a = xr[k];
        int c = yc[(size_t)k * N];
        dot += a * c; sx += a; sy += c;
    }
    float s = xsp[0] * ysp[0];
    out[idx] = s * (float)(dot - 160 * sx + 66 * sy - 10813440);
}

// ---------------------------------------------------------------------------
extern "C" void kernel_launch(void* const* d_in, const int* in_sizes, int n_in,
                              void* d_out, int out_size, void* d_ws, size_t ws_size,
                              hipStream_t stream) {
    const int*   x  = (const int*)d_in[0];     // [7,8,512,1024] int8 values in int32
    const int*   y  = (const int*)d_in[1];     // [8,1024,512] uint8 values in int32
    const float* xs = (const float*)d_in[2];
    const float* ys = (const float*)d_in[3];
    float* out = (float*)d_out;

    if (ws_size < WS_NEEDED) {
        naive_kernel<<<(14680064 + 255) / 256, 256, 0, stream>>>(x, y, xs, ys, out);
        return;
    }

    char* ws = (char*)d_ws;
    signed char* yt  = (signed char*)ws;
    int*         csp = (int*)(ws + YT_BYTES);

    transpose_pack_y<<<dim3(N / 64, K / 64, B), 256, 0, stream>>>(y, yt, csp);
    gemm_fused<<<dim3(448), 512, 0, stream>>>(x, yt, csp, xs, ys, out);
}

// Round 9
// 230.794 us; speedup vs baseline: 1.1350x; 1.1350x over previous
//
#include <hip/hip_runtime.h>
#include <stdint.h>

#define AS1 __attribute__((address_space(1)))
#define AS3 __attribute__((address_space(3)))

typedef int v4i __attribute__((ext_vector_type(4)));

// Problem constants (from reference)
constexpr int G = 7, B = 8, M = 512, N = 512, K = 1024;
constexpr int GBn = G * B;                       // 56
// X_ZP = -66, Y_ZP = 160 (hardcoded in reference)
// With y' = y - 128:  sum (x-X)(y-Y) = dot(x,y') - 32*rowsum_x + 66*colsum_y' - 2162688

// ws layout: x8 | yt | csp | rowsum
constexpr size_t X8_BYTES = (size_t)GBn * M * K;  // 29,360,128  packed x int8
constexpr size_t YT_BYTES = (size_t)B * N * K;    //  4,194,304  yt [b][n][k] int8 (y-128)
constexpr size_t CSP_CNT  = (size_t)16 * B * N;   //  65,536 ints: per-k-tile colsum partials
constexpr size_t RS_CNT   = (size_t)GBn * M;      //  28,672 ints: rowsums
constexpr size_t WS_NEEDED = X8_BYTES + YT_BYTES + CSP_CNT * 4 + RS_CNT * 4;

// ---------------------------------------------------------------------------
// K1: transpose + pack y:  y[b][k][n] (int32, 0..255)  ->  yt[b][n][k] (int8, y-128)
// plus per-(k-tile, b, n) partial colsums of y' into csp.
// 64x64 tiles through LDS. Grid: (N/64, K/64, B), block 256.
// ---------------------------------------------------------------------------
__global__ __launch_bounds__(256) void transpose_pack_y(const int* __restrict__ y,
                                                        signed char* __restrict__ yt,
                                                        int* __restrict__ csp) {
    __shared__ unsigned char tile[64][80];       // 80 = 5*16: 16B-aligned rows, odd 16-bank phase
    int n0  = blockIdx.x * 64;
    int k0t = blockIdx.y;
    int k0  = k0t * 64;
    int b   = blockIdx.z;
    int t   = threadIdx.x;

    // phase 1: coalesced read along n, pack low bytes (^0x80 == y-128 as i8), 16B to LDS
    int r  = t >> 2;                              // k-local 0..63
    int c0 = (t & 3) * 16;                        // n-local byte offset
    const int* src = y + ((size_t)b * K + k0 + r) * N + n0 + c0;
    uint32_t p[4];
#pragma unroll
    for (int q = 0; q < 4; ++q) {
        int4 v = ((const int4*)src)[q];
        p[q] =  (uint32_t)((v.x & 255) ^ 128)
             | ((uint32_t)((v.y & 255) ^ 128) << 8)
             | ((uint32_t)((v.z & 255) ^ 128) << 16)
             | ((uint32_t)((v.w & 255) ^ 128) << 24);
    }
    *(uint4*)&tile[r][c0] = make_uint4(p[0], p[1], p[2], p[3]);
    __syncthreads();

    // phase 2: gather a column of 16 k-bytes per thread, write 16B contiguous in k
    int nl = t >> 2;                              // n-local 0..63
    int kc = (t & 3) * 16;                        // k-local byte offset
    uint32_t q[4];
    int s = 0;
#pragma unroll
    for (int w = 0; w < 4; ++w) {
        uint32_t b0 = tile[kc + w * 4 + 0][nl];
        uint32_t b1 = tile[kc + w * 4 + 1][nl];
        uint32_t b2 = tile[kc + w * 4 + 2][nl];
        uint32_t b3 = tile[kc + w * 4 + 3][nl];
        s += (int)(signed char)b0 + (int)(signed char)b1
           + (int)(signed char)b2 + (int)(signed char)b3;
        q[w] = b0 | (b1 << 8) | (b2 << 16) | (b3 << 24);
    }
    *(uint4*)(yt + ((size_t)b * N + n0 + nl) * K + k0 + kc) = make_uint4(q[0], q[1], q[2], q[3]);

    // quad-reduce partial colsum (4 threads cover 64 k for one n)
    s += __shfl_xor(s, 1, 64);
    s += __shfl_xor(s, 2, 64);
    if ((t & 3) == 0) csp[(size_t)k0t * (B * N) + b * N + n0 + nl] = s;
}

// ---------------------------------------------------------------------------
// K2: pack x int32 -> int8 + rowsum(x). One wave per 4KB row: 64 lanes x 64B
// CONTIGUOUS -- the DRAM-friendly streaming read of x (the whole point: the
// fused variants read x as 64B-per-4KB-stride slices, which page-thrashed HBM
// at ~1.6-2 TB/s and was the session-invariant wall; FETCH=73MB proved x
// misses L3 every iteration because the harness's 470MB poison fills flush
// the LLC). Grid: 7168 blocks x 256 (4 waves, 4 rows/block).
// ---------------------------------------------------------------------------
__global__ __launch_bounds__(256) void pack_x(const int* __restrict__ x,
                                              signed char* __restrict__ x8,
                                              int* __restrict__ rowsum) {
    int wave = threadIdx.x >> 6, lane = threadIdx.x & 63;
    int row = blockIdx.x * 4 + wave;              // 0..28671
    const int4* src = (const int4*)(x + (size_t)row * K) + lane * 4;   // 64B per lane
    int s = 0;
    uint32_t p[4];
#pragma unroll
    for (int q = 0; q < 4; ++q) {
        int4 v = src[q];
        s += v.x + v.y + v.z + v.w;
        p[q] =  (uint32_t)(v.x & 255)
             | ((uint32_t)(v.y & 255) << 8)
             | ((uint32_t)(v.z & 255) << 16)
             | ((uint32_t)(v.w & 255) << 24);
    }
    *(uint4*)(x8 + (size_t)row * K + lane * 16) = make_uint4(p[0], p[1], p[2], p[3]);
#pragma unroll
    for (int off = 32; off > 0; off >>= 1) s += __shfl_down(s, off, 64);
    if (lane == 0) rowsum[row] = s;
}

// ---------------------------------------------------------------------------
// K3: i8 GEMM, the round-1 structure (session best) with A staged from the
// L3-RESIDENT x8 (written this iteration by K2 -- the poison fills flush LLC
// only BETWEEN harness iterations). Block = 128m x 512n for one (gb, mt);
// 512 threads, 8 waves (2m x 4n), wave 64x128 via 4x8 mfma_i32_16x16x64_i8;
// 2 waves/SIMD (256-reg budget). Per step: A 8KB (1 gload_lds/wave, L3-hit)
// + B 32KB (4 gload_lds/wave, L2-resident yt) -- no in-register packing, no
// HBM dependency in the K-loop. Single __syncthreads per step (R7 proved
// counted-vmcnt is null). LDS swizzle as R1: slot p of each 64B row holds
// k-chunk p^((row>>1)&3), staged via pre-swizzled SOURCE chunks (gload_lds
// dest is linear); readers use fk = ((lane>>4)^((fr>>1)&3))*16.
// LDS: 16K (As) + 64K (Bs) + 2K = 82K -> 1 block/CU.
// Grid: 224 = 56 gb x 4 mt, XCD-bijective swizzle (per-XCD yt slices 3.5MB
// < 4MB L2).
// ---------------------------------------------------------------------------
__global__ __launch_bounds__(512, 2) void gemm_i8(const signed char* __restrict__ x8,
                                                  const signed char* __restrict__ yt,
                                                  const int* __restrict__ rowsum,
                                                  const int* __restrict__ csp,
                                                  const float* __restrict__ xsp,
                                                  const float* __restrict__ ysp,
                                                  float* __restrict__ out) {
    __shared__ __align__(16) signed char As[2][128 * 64];   // 16 KiB
    __shared__ __align__(16) signed char Bs[2][512 * 64];   // 64 KiB
    __shared__ int cs_lds[512];

    int id  = blockIdx.x;                         // 0..223
    int swz = (id & 7) * 28 + (id >> 3);          // XCD-contiguous chunks (224%8==0, bijective)
    int gb  = swz >> 2;                           // 0..55
    int mt  = swz & 3;                            // 0..3
    int b   = gb & 7;

    int tid = threadIdx.x, wave = tid >> 6, lane = tid & 63;

    // block colsums: each thread sums 16 per-k-tile partials for one n
    {
        int s = 0;
        const int* p = csp + b * N + tid;
#pragma unroll
        for (int kt = 0; kt < 16; ++kt) s += p[(size_t)kt * (B * N)];
        cs_lds[tid] = s;
    }

    // A staging: wave w stages rows w*16 + (lane>>2); source chunk swizzled.
    // dest slot p = lane&3 at row r=w*16+(lane>>2) must hold chunk
    // p ^ ((r>>1)&3) = (lane&3) ^ ((lane>>3)&3)  (w*16>>1 == 0 mod 4).
    int srow   = lane >> 2;
    int schunk = (lane & 3) ^ ((lane >> 3) & 3);
    const signed char* Asrc = x8 + ((size_t)(gb * M + mt * 128 + wave * 16 + srow)) * K + schunk * 16;

    // B staging: per wave, call c stages rows c*128 + wave*16 + (lane>>2)
    int brl    = lane >> 2;
    int bchunk = (lane & 3) ^ ((lane >> 3) & 3);
    const signed char* Bsrc = yt + ((size_t)b * N) * K;

    // fragment read offsets
    int fr = lane & 15;
    int fk = ((lane >> 4) ^ ((fr >> 1) & 3)) << 4;
    int wm = (wave >> 2) * 64;                    // 0 or 64
    int wn = (wave & 3) * 128;                    // 0,128,256,384

    v4i zero = {0, 0, 0, 0};
    v4i acc[4][8];
#pragma unroll
    for (int i = 0; i < 4; ++i)
#pragma unroll
        for (int j = 0; j < 8; ++j) acc[i][j] = zero;

    // prologue: stage A(0), B(0) -> buf 0
    __builtin_amdgcn_global_load_lds((const AS1 uint32_t*)(Asrc),
                                     (AS3 uint32_t*)(&As[0][wave * 1024]), 16, 0, 0);
#pragma unroll
    for (int c = 0; c < 4; ++c) {
        __builtin_amdgcn_global_load_lds(
            (const AS1 uint32_t*)(Bsrc + (size_t)(c * 128 + wave * 16 + brl) * K + bchunk * 16),
            (AS3 uint32_t*)(&Bs[0][(c * 128 + wave * 16) * 64]), 16, 0, 0);
    }

#pragma unroll 2
    for (int t = 0; t < 16; ++t) {
        int cur = t & 1;

        __syncthreads();   // drains A(t)+B(t) gloads: buf[cur] ready

        // issue next step's staging into the OTHER buffer: its last readers
        // (step t-1) completed before the barrier above. Loads fly under
        // this step's ds_reads + MFMAs; next barrier drains them.
        if (t < 15) {
            __builtin_amdgcn_global_load_lds(
                (const AS1 uint32_t*)(Asrc + (t + 1) * 64),
                (AS3 uint32_t*)(&As[cur ^ 1][wave * 1024]), 16, 0, 0);
#pragma unroll
            for (int c = 0; c < 4; ++c) {
                __builtin_amdgcn_global_load_lds(
                    (const AS1 uint32_t*)(Bsrc + (size_t)(c * 128 + wave * 16 + brl) * K
                                          + (t + 1) * 64 + bchunk * 16),
                    (AS3 uint32_t*)(&Bs[cur ^ 1][(c * 128 + wave * 16) * 64]), 16, 0, 0);
            }
        }

        v4i af[4], bf[8];
#pragma unroll
        for (int i = 0; i < 4; ++i)
            af[i] = *(const v4i*)(&As[cur][(wm + i * 16 + fr) * 64 + fk]);
#pragma unroll
        for (int j = 0; j < 8; ++j)
            bf[j] = *(const v4i*)(&Bs[cur][(wn + j * 16 + fr) * 64 + fk]);

#pragma unroll
        for (int i = 0; i < 4; ++i)
#pragma unroll
            for (int j = 0; j < 8; ++j)
                acc[i][j] = __builtin_amdgcn_mfma_i32_16x16x64_i8(af[i], bf[j], acc[i][j], 0, 0, 0);
    }

    // epilogue: C = s * (dot - 32*rowsum_x + 66*colsum_y' - 2162688)
    float sc = xsp[0] * ysp[0];
    int colL = lane & 15;
    int rowQ = (lane >> 4) * 4;
    float* outg = out + (size_t)gb * (M * N) + (size_t)(mt * 128) * N;
    const int* rs = rowsum + gb * M + mt * 128;
#pragma unroll
    for (int i = 0; i < 4; ++i) {
#pragma unroll
        for (int r = 0; r < 4; ++r) {
            int row_l = wm + i * 16 + rowQ + r;
            int rsv = rs[row_l];
#pragma unroll
            for (int j = 0; j < 8; ++j) {
                int col = wn + j * 16 + colL;
                int tv = acc[i][j][r] - 32 * rsv + 66 * cs_lds[col] - 2162688;
                outg[(size_t)row_l * N + col] = sc * (float)tv;
            }
        }
    }
}

// ---------------------------------------------------------------------------
// Fallback (only if ws_size is too small): naive but correct.
// sum (x-X)(y-Y) = dot(x,y) - 160*sum_x + 66*sum_y - 10,813,440
// ---------------------------------------------------------------------------
__global__ __launch_bounds__(256) void naive_kernel(const int* __restrict__ x,
                                                    const int* __restrict__ y,
                                                    const float* __restrict__ xsp,
                                                    const float* __restrict__ ysp,
                                                    float* __restrict__ out) {
    size_t idx = (size_t)blockIdx.x * 256 + threadIdx.x;   // over 14,680,064
    int n  = (int)(idx & 511);
    int m  = (int)((idx >> 9) & 511);
    int gb = (int)(idx >> 18);
    int b  = gb & 7;
    const int* xr = x + ((size_t)gb * M + m) * K;
    const int* yc = y + (size_t)b * K * N + n;
    int dot = 0, sx = 0, sy = 0;
    for (int k = 0; k < K; ++k) {
        int a = xr[k];
        int c = yc[(size_t)k * N];
        dot += a * c; sx += a; sy += c;
    }
    float s = xsp[0] * ysp[0];
    out[idx] = s * (float)(dot - 160 * sx + 66 * sy - 10813440);
}

// ---------------------------------------------------------------------------
extern "C" void kernel_launch(void* const* d_in, const int* in_sizes, int n_in,
                              void* d_out, int out_size, void* d_ws, size_t ws_size,
                              hipStream_t stream) {
    const int*   x  = (const int*)d_in[0];     // [7,8,512,1024] int8 values in int32
    const int*   y  = (const int*)d_in[1];     // [8,1024,512] uint8 values in int32
    const float* xs = (const float*)d_in[2];
    const float* ys = (const float*)d_in[3];
    float* out = (float*)d_out;

    if (ws_size < WS_NEEDED) {
        naive_kernel<<<(14680064 + 255) / 256, 256, 0, stream>>>(x, y, xs, ys, out);
        return;
    }

    char* ws = (char*)d_ws;
    signed char* x8  = (signed char*)ws;
    signed char* yt  = (signed char*)(ws + X8_BYTES);
    int*         csp = (int*)(ws + X8_BYTES + YT_BYTES);
    int*         rsm = csp + CSP_CNT;

    transpose_pack_y<<<dim3(N / 64, K / 64, B), 256, 0, stream>>>(y, yt, csp);
    pack_x<<<GBn * M / 4, 256, 0, stream>>>(x, x8, rsm);
    gemm_i8<<<dim3(224), 512, 0, stream>>>(x8, yt, rsm, csp, xs, ys, out);
}

// Round 10
// 217.201 us; speedup vs baseline: 1.2060x; 1.0626x over previous
//
#include <hip/hip_runtime.h>
#include <stdint.h>

#define AS1 __attribute__((address_space(1)))
#define AS3 __attribute__((address_space(3)))

typedef int v4i __attribute__((ext_vector_type(4)));

// Problem constants (from reference)
constexpr int G = 7, B = 8, M = 512, N = 512, K = 1024;
constexpr int GBn = G * B;                       // 56
// X_ZP = -66, Y_ZP = 160 (hardcoded in reference)
// With y' = y - 128:  sum (x-X)(y-Y) = dot(x,y') - 32*rowsum_x + 66*colsum_y' - 2162688

// ws layout: yt [b][n][k] int8 (y-128), then csp[16][B*N] per-k-tile colsum partials
constexpr size_t YT_BYTES = (size_t)B * N * K;   // 4,194,304
constexpr size_t CSP_CNT  = (size_t)16 * B * N;  // 65,536 ints
constexpr size_t WS_NEEDED = YT_BYTES + CSP_CNT * 4;

// ---------------------------------------------------------------------------
// K1: transpose + pack y:  y[b][k][n] (int32, 0..255)  ->  yt[b][n][k] (int8, y-128)
// plus per-(k-tile, b, n) partial colsums of y' into csp.
// 64x64 tiles through LDS. Grid: (N/64, K/64, B), block 256.
// ---------------------------------------------------------------------------
__global__ __launch_bounds__(256) void transpose_pack_y(const int* __restrict__ y,
                                                        signed char* __restrict__ yt,
                                                        int* __restrict__ csp) {
    __shared__ unsigned char tile[64][80];       // 80 = 5*16: 16B-aligned rows, odd 16-bank phase
    int n0  = blockIdx.x * 64;
    int k0t = blockIdx.y;
    int k0  = k0t * 64;
    int b   = blockIdx.z;
    int t   = threadIdx.x;

    // phase 1: coalesced read along n, pack low bytes (^0x80 == y-128 as i8), 16B to LDS
    int r  = t >> 2;                              // k-local 0..63
    int c0 = (t & 3) * 16;                        // n-local byte offset
    const int* src = y + ((size_t)b * K + k0 + r) * N + n0 + c0;
    uint32_t p[4];
#pragma unroll
    for (int q = 0; q < 4; ++q) {
        int4 v = ((const int4*)src)[q];
        p[q] =  (uint32_t)((v.x & 255) ^ 128)
             | ((uint32_t)((v.y & 255) ^ 128) << 8)
             | ((uint32_t)((v.z & 255) ^ 128) << 16)
             | ((uint32_t)((v.w & 255) ^ 128) << 24);
    }
    *(uint4*)&tile[r][c0] = make_uint4(p[0], p[1], p[2], p[3]);
    __syncthreads();

    // phase 2: gather a column of 16 k-bytes per thread, write 16B contiguous in k
    int nl = t >> 2;                              // n-local 0..63
    int kc = (t & 3) * 16;                        // k-local byte offset
    uint32_t q[4];
    int s = 0;
#pragma unroll
    for (int w = 0; w < 4; ++w) {
        uint32_t b0 = tile[kc + w * 4 + 0][nl];
        uint32_t b1 = tile[kc + w * 4 + 1][nl];
        uint32_t b2 = tile[kc + w * 4 + 2][nl];
        uint32_t b3 = tile[kc + w * 4 + 3][nl];
        s += (int)(signed char)b0 + (int)(signed char)b1
           + (int)(signed char)b2 + (int)(signed char)b3;
        q[w] = b0 | (b1 << 8) | (b2 << 16) | (b3 << 24);
    }
    *(uint4*)(yt + ((size_t)b * N + n0 + nl) * K + k0 + kc) = make_uint4(q[0], q[1], q[2], q[3]);

    // quad-reduce partial colsum (4 threads cover 64 k for one n)
    s += __shfl_xor(s, 1, 64);
    s += __shfl_xor(s, 2, 64);
    if ((t & 3) == 0) csp[(size_t)k0t * (B * N) + b * N + n0 + nl] = s;
}

// ---------------------------------------------------------------------------
// K2 (fused GEMM), round-10: TWO INDEPENDENT BARRIER DOMAINS PER CU.
//
// Evidence chain: bytes (R9: 4x fewer gemm read bytes ~ null), occupancy
// (R3), stagger (R6), counted-vmcnt (R7), access pattern (R5/R8) -- all
// null/negative. Surviving model: per-CU read-path concurrency. One block's
// step = issue ~64KB burst -> ALL waves park at one barrier until the last
// line returns -> outstanding-request pool drains, bursty service, ~14GB/s
// per CU (~3.6TB/s chip). Fix: 2 blocks/CU with DECOUPLED barriers at
// byte-identical traffic and full 256-reg budget (unlike R2, which bundled
// 2 blocks/CU with 2x x-traffic and a 128-reg cap).
//
// Block = 64m x 512n (full N) for one (gb, mt): 256 threads, 4 waves, each
// wave 64x128 via 4x8 mfma_i32_16x16x64_i8 (acc = 128 AGPR).
// __launch_bounds__(256,2): 2 waves/SIMD -> 256 unified regs; LDS 74.25KB
// -> 2 blocks/CU (148.5KB <= 160KB). Per-CU waves = 8, same as R1; only the
// barrier coupling changes.
//
// A read from x (int32) ONCE (448 blocks x 64 rows = each row exactly once),
// packed in-register -> swizzled ds_write; rowsums inline. B staged via
// global_load_lds from yt (pre-swizzled source chunks; per wave 8 calls of
// 16 rows = 128 rows/step). Double-buffered LDS, ONE __syncthreads per step,
// t+1 prefetch issued right after the barrier (R1's verified schedule).
// LDS swizzle: slot p of each 64B row holds k-chunk p^((row>>1)&3); readers
// use fk = ((lane>>4)^((fr>>1)&3))*16 -> 2-way bank alias = free.
// Grid: 448 = 56 gb x 8 mt, XCD-bijective swizzle (per-XCD yt 3.5MB < 4MB L2).
// BN=512 keeps output writes line-exact (R2 showed BN=256 doubles WRITE).
// ---------------------------------------------------------------------------
__global__ __launch_bounds__(256, 2) void gemm_fused(const int* __restrict__ x,
                                                     const signed char* __restrict__ yt,
                                                     const int* __restrict__ csp,
                                                     const float* __restrict__ xsp,
                                                     const float* __restrict__ ysp,
                                                     float* __restrict__ out) {
    __shared__ __align__(16) signed char As[2][64 * 64];    //  8 KiB
    __shared__ __align__(16) signed char Bs[2][512 * 64];   // 64 KiB
    __shared__ int cs_lds[512];
    __shared__ int rs_lds[64];

    int id  = blockIdx.x;                         // 0..447
    int swz = (id & 7) * 56 + (id >> 3);          // XCD-contiguous chunks (448%8==0, bijective)
    int gb  = swz >> 3;                           // 0..55
    int mt  = swz & 7;                            // 0..7
    int b   = gb & 7;

    int tid = threadIdx.x, wave = tid >> 6, lane = tid & 63;

    // block colsums: each thread sums partials for two n's
    {
        const int* p = csp + b * N;
#pragma unroll
        for (int half = 0; half < 2; ++half) {
            int n = tid + half * 256;
            int s = 0;
#pragma unroll
            for (int kt = 0; kt < 16; ++kt) s += p[(size_t)kt * (B * N) + n];
            cs_lds[n] = s;
        }
    }

    // A staging: thread t handles row t>>2 (0..63), k-quad t&3 (16 ints = 64B src)
    int arow = tid >> 2;
    int akq  = tid & 3;
    const int4* Asrc = (const int4*)(x + ((size_t)(gb * M + mt * 64 + arow)) * K) + akq * 4;
    int aoff = arow * 64 + ((akq ^ ((arow >> 1) & 3)) << 4);   // swizzled ds_write addr

    // B staging: wave w, call c stages rows c*64 + w*16 + (lane>>2), c=0..7
    int brl    = lane >> 2;
    int bchunk = (lane & 3) ^ ((lane >> 3) & 3);               // pre-swizzled source chunk
    const signed char* Bsrc = yt + ((size_t)b * N) * K;

    // fragment read offsets
    int fr = lane & 15;
    int fk = ((lane >> 4) ^ ((fr >> 1) & 3)) << 4;
    int wn = wave * 128;                          // 0,128,256,384 (wm = 0: wave spans all 64 rows)

    v4i zero = {0, 0, 0, 0};
    v4i acc[4][8];
#pragma unroll
    for (int i = 0; i < 4; ++i)
#pragma unroll
        for (int j = 0; j < 8; ++j) acc[i][j] = zero;

    int rsum = 0;

    // prologue: A(0) -> regs, B(0) -> Bs[0]
    int4 av[4];
#pragma unroll
    for (int q = 0; q < 4; ++q) av[q] = Asrc[q];
#pragma unroll
    for (int c = 0; c < 8; ++c) {
        __builtin_amdgcn_global_load_lds(
            (const AS1 uint32_t*)(Bsrc + (size_t)(c * 64 + wave * 16 + brl) * K + bchunk * 16),
            (AS3 uint32_t*)(&Bs[0][(c * 64 + wave * 16) * 64]), 16, 0, 0);
    }

#pragma unroll 2
    for (int t = 0; t < 16; ++t) {
        int cur = t & 1;

        // pack A(t) -> LDS, accumulate rowsum (vmcnt waits only for av)
        uint32_t pw[4];
        int s = 0;
#pragma unroll
        for (int q = 0; q < 4; ++q) {
            int4 v = av[q];
            s += v.x + v.y + v.z + v.w;
            pw[q] =  (uint32_t)(v.x & 255)
                 | ((uint32_t)(v.y & 255) << 8)
                 | ((uint32_t)(v.z & 255) << 16)
                 | ((uint32_t)(v.w & 255) << 24);
        }
        rsum += s;
        *(uint4*)(&As[cur][aoff]) = make_uint4(pw[0], pw[1], pw[2], pw[3]);

        __syncthreads();   // drains B(t) gloads + A(t) ds_writes: buf[cur] ready

        // issue next step's loads (av first, then B): they fly under
        // ds_reads + MFMAs and are drained by the NEXT barrier.
        if (t < 15) {
#pragma unroll
            for (int q = 0; q < 4; ++q) av[q] = Asrc[(t + 1) * 16 + q];
#pragma unroll
            for (int c = 0; c < 8; ++c) {
                __builtin_amdgcn_global_load_lds(
                    (const AS1 uint32_t*)(Bsrc + (size_t)(c * 64 + wave * 16 + brl) * K
                                          + (t + 1) * 64 + bchunk * 16),
                    (AS3 uint32_t*)(&Bs[cur ^ 1][(c * 64 + wave * 16) * 64]), 16, 0, 0);
            }
        }

        v4i af[4], bf[8];
#pragma unroll
        for (int i = 0; i < 4; ++i)
            af[i] = *(const v4i*)(&As[cur][(i * 16 + fr) * 64 + fk]);
#pragma unroll
        for (int j = 0; j < 8; ++j)
            bf[j] = *(const v4i*)(&Bs[cur][(wn + j * 16 + fr) * 64 + fk]);

#pragma unroll
        for (int i = 0; i < 4; ++i)
#pragma unroll
            for (int j = 0; j < 8; ++j)
                acc[i][j] = __builtin_amdgcn_mfma_i32_16x16x64_i8(af[i], bf[j], acc[i][j], 0, 0, 0);
        // no second barrier: next step writes the OTHER buffer; the single
        // block-wide barrier above orders read(t-1) < write(t+1).
    }

    // rowsum: quad-reduce (4 threads per row), publish to LDS
    rsum += __shfl_xor(rsum, 1, 64);
    rsum += __shfl_xor(rsum, 2, 64);
    if ((tid & 3) == 0) rs_lds[arow] = rsum;
    __syncthreads();

    // epilogue: C = s * (dot - 32*rowsum_x + 66*colsum_y' - 2162688)
    float sc = xsp[0] * ysp[0];
    int colL = lane & 15;
    int rowQ = (lane >> 4) * 4;
    float* outg = out + (size_t)gb * (M * N) + (size_t)(mt * 64) * N;
#pragma unroll
    for (int i = 0; i < 4; ++i) {
#pragma unroll
        for (int r = 0; r < 4; ++r) {
            int row_l = i * 16 + rowQ + r;
            int rsv = rs_lds[row_l];
#pragma unroll
            for (int j = 0; j < 8; ++j) {
                int col = wn + j * 16 + colL;
                int tv = acc[i][j][r] - 32 * rsv + 66 * cs_lds[col] - 2162688;
                outg[(size_t)row_l * N + col] = sc * (float)tv;
            }
        }
    }
}

// ---------------------------------------------------------------------------
// Fallback (only if ws_size is too small): naive but correct.
// sum (x-X)(y-Y) = dot(x,y) - 160*sum_x + 66*sum_y - 10,813,440
// ---------------------------------------------------------------------------
__global__ __launch_bounds__(256) void naive_kernel(const int* __restrict__ x,
                                                    const int* __restrict__ y,
                                                    const float* __restrict__ xsp,
                                                    const float* __restrict__ ysp,
                                                    float* __restrict__ out) {
    size_t idx = (size_t)blockIdx.x * 256 + threadIdx.x;   // over 14,680,064
    int n  = (int)(idx & 511);
    int m  = (int)((idx >> 9) & 511);
    int gb = (int)(idx >> 18);
    int b  = gb & 7;
    const int* xr = x + ((size_t)gb * M + m) * K;
    const int* yc = y + (size_t)b * K * N + n;
    int dot = 0, sx = 0, sy = 0;
    for (int k = 0; k < K; ++k) {
        int a = xr[k];
        int c = yc[(size_t)k * N];
        dot += a * c; sx += a; sy += c;
    }
    float s = xsp[0] * ysp[0];
    out[idx] = s * (float)(dot - 160 * sx + 66 * sy - 10813440);
}

// ---------------------------------------------------------------------------
extern "C" void kernel_launch(void* const* d_in, const int* in_sizes, int n_in,
                              void* d_out, int out_size, void* d_ws, size_t ws_size,
                              hipStream_t stream) {
    const int*   x  = (const int*)d_in[0];     // [7,8,512,1024] int8 values in int32
    const int*   y  = (const int*)d_in[1];     // [8,1024,512] uint8 values in int32
    const float* xs = (const float*)d_in[2];
    const float* ys = (const float*)d_in[3];
    float* out = (float*)d_out;

    if (ws_size < WS_NEEDED) {
        naive_kernel<<<(14680064 + 255) / 256, 256, 0, stream>>>(x, y, xs, ys, out);
        return;
    }

    char* ws = (char*)d_ws;
    signed char* yt  = (signed char*)ws;
    int*         csp = (int*)(ws + YT_BYTES);

    transpose_pack_y<<<dim3(N / 64, K / 64, B), 256, 0, stream>>>(y, yt, csp);
    gemm_fused<<<dim3(448), 256, 0, stream>>>(x, yt, csp, xs, ys, out);
}